// Round 5
// baseline (103.711 us; speedup 1.0000x reference)
//
#include <hip/hip_runtime.h>

typedef __bf16 bf16x8 __attribute__((ext_vector_type(8)));
typedef __bf16 bf16x2 __attribute__((ext_vector_type(2)));
typedef float  f32x4  __attribute__((ext_vector_type(4)));

// ws layout (bytes). All A-operand fragments lane-linear:
// one frag = 1024 B; lane l's 16 B at frag_base + l*16.
//   WT0 : 8 frags   (nt 0..7)            bytes [0      .. 8191  ]
//   WTH : 160 frags ((h*4+ks)*8 + nt)    bytes [8192   .. 172031]
//   WLT : 4 frags   (ks 0..3)            bytes [172032 .. 176127]
#define WS_WT0_B 0
#define WS_WTH_B 8192
#define WS_WLT_B 172032

__device__ __forceinline__ unsigned short f2b(float f) {
  return __builtin_bit_cast(unsigned short, (__bf16)f);
}

__global__ void prep_kernel(const float* __restrict__ W0,
                            const float* __restrict__ Wh,
                            const float* __restrict__ WL,
                            unsigned short* __restrict__ ws) {
  int i = blockIdx.x * 256 + threadIdx.x;   // ushort index == (byte/2)
  int l  = (i >> 3) & 63;                   // lane within frag
  int j  = i & 7;                           // element within lane's 8
  int lm = l & 15, lh = l >> 4;
  if (i < 4096) {                           // WT0, frag nt = i>>9 ; K=32 zero-padded
    int nt = i >> 9;
    int n = nt * 16 + lm, k = lh * 8 + j;
    ws[i] = f2b(k < 4 ? W0[k * 128 + n] : 0.f);
  } else if (i < 86016) {                   // WTH
    int t = i - 4096;
    int frag = t >> 9;                      // (h*4+ks)*8 + nt
    int nt = frag & 7, ks = (frag >> 3) & 3, h = frag >> 5;
    int n = nt * 16 + lm, k = ks * 32 + lh * 8 + j;
    ws[i] = f2b(Wh[(h * 128 + k) * 128 + n]);
  } else if (i < 88064) {                   // WLT, frag ks ; n>=2 zero-padded
    int t = i - 86016;
    int ks = t >> 9;
    int n = lm, k = ks * 32 + lh * 8 + j;
    ws[i] = f2b(n < 2 ? WL[k * 2 + n] : 0.f);
  }
}

__device__ __forceinline__ f32x4 swish4(f32x4 z) {
  f32x4 e;
  e[0] = __expf(-z[0]); e[1] = __expf(-z[1]);
  e[2] = __expf(-z[2]); e[3] = __expf(-z[3]);
  const f32x4 w = e + 1.f;
  f32x4 s;
  s[0] = __builtin_amdgcn_rcpf(w[0]); s[1] = __builtin_amdgcn_rcpf(w[1]);
  s[2] = __builtin_amdgcn_rcpf(w[2]); s[3] = __builtin_amdgcn_rcpf(w[3]);
  return z * s;
}

// pack f32x4 -> 2x u32 of bf16 pairs (v_cvt_pk_bf16_f32 path)
__device__ __forceinline__ uint2 pack4(f32x4 r) {
  bf16x2 lo = {(__bf16)r[0], (__bf16)r[1]};
  bf16x2 hi = {(__bf16)r[2], (__bf16)r[3]};
  uint2 wv;
  wv.x = __builtin_bit_cast(unsigned int, lo);
  wv.y = __builtin_bit_cast(unsigned int, hi);
  return wv;
}

// 2 independent waves per 128-thread block (no barriers); each wave owns 32 pts.
// 16 KB LDS/block -> 10 blocks/CU -> 20 waves/CU.
__launch_bounds__(128, 5)
__global__ void mlp_kernel(const float* __restrict__ X,
                           const float* __restrict__ nu_min_p,
                           const float* __restrict__ nu_max_p,
                           const float* __restrict__ b0,
                           const float* __restrict__ bh,
                           const float* __restrict__ bL,
                           const unsigned short* __restrict__ ws,
                           float* __restrict__ out) {
  __shared__ __align__(16) char HsAll[2][32 * 256];  // 8 KB per wave
  const int lane = threadIdx.x & 63;
  const int wave = threadIdx.x >> 6;
  char* Hs = HsAll[wave];
  const int lm = lane & 15, lh = lane >> 4;
  const int row0 = blockIdx.x * 64 + wave * 32;
  const char* wsb = reinterpret_cast<const char*>(ws);
  const char* ap  = wsb + lane * 16;            // per-lane A-frag pointer
  const int xorm = (lm & 7) << 4;

  // precomputed LDS addrs: rd(pt,ks) = va[pt] ^ (ks<<6); wr(nt,pt) = wa[pt] ^ (nt<<5)
  const int va0 = lm * 256 + ((lh * 16) ^ xorm);
  const int va1 = va0 + 16 * 256;
  const int wa0 = lm * 256 + ((lh * 8) ^ xorm);
  const int wa1 = wa0 + 16 * 256;

  // ---- stage scaled inputs (K padded to 32 -> 64B rows) ----
  if (lane < 32) {
    const float4 xv = reinterpret_cast<const float4*>(X)[row0 + lane];
    const float numin = nu_min_p[0], numax = nu_max_p[0];
    const float v0 = xv.x;
    const float v1 = xv.y;
    const float v2 = 2.f * xv.z - 1.f;
    const float v3 = 2.f * (xv.w - numin) / (numax - numin) - 1.f;
    uint4 c0;
    c0.x = (unsigned)f2b(v0) | ((unsigned)f2b(v1) << 16);
    c0.y = (unsigned)f2b(v2) | ((unsigned)f2b(v3) << 16);
    c0.z = 0u; c0.w = 0u;
    const uint4 z4 = make_uint4(0u, 0u, 0u, 0u);
    const int xr = (lane & 7) << 4;
    char* rp = Hs + lane * 256;
    *reinterpret_cast<uint4*>(rp + (0  ^ xr)) = c0;
    *reinterpret_cast<uint4*>(rp + (16 ^ xr)) = z4;
    *reinterpret_cast<uint4*>(rp + (32 ^ xr)) = z4;
    *reinterpret_cast<uint4*>(rp + (48 ^ xr)) = z4;
  }

  f32x4 acc[8][2];

  // ================= Layer 0 : K = 32 (single ks) =================
  {
    __builtin_amdgcn_s_setprio(1);
    bf16x8 bfr[2];
    bfr[0] = __builtin_bit_cast(bf16x8, *reinterpret_cast<const uint4*>(Hs + va0));
    bfr[1] = __builtin_bit_cast(bf16x8, *reinterpret_cast<const uint4*>(Hs + va1));
#pragma unroll
    for (int nt = 0; nt < 8; ++nt) {
      const f32x4 bv = *reinterpret_cast<const f32x4*>(b0 + nt * 16 + lh * 4);
      const bf16x8 a = __builtin_bit_cast(bf16x8,
          *reinterpret_cast<const uint4*>(ap + WS_WT0_B + nt * 1024));
      acc[nt][0] = __builtin_amdgcn_mfma_f32_16x16x32_bf16(a, bfr[0], bv, 0, 0, 0);
      acc[nt][1] = __builtin_amdgcn_mfma_f32_16x16x32_bf16(a, bfr[1], bv, 0, 0, 0);
    }
    __builtin_amdgcn_s_setprio(0);
#pragma unroll
    for (int nt = 0; nt < 8; ++nt) {
#pragma unroll
      for (int pt = 0; pt < 2; ++pt) {
        const uint2 wv = pack4(swish4(acc[nt][pt]));
        const int wa = (pt ? wa1 : wa0) ^ (nt << 5);
        *reinterpret_cast<uint2*>(Hs + wa) = wv;
      }
    }
  }

  // ================= 5 hidden layers : K = 128, in-place =================
#pragma unroll 1
  for (int h = 0; h < 5; ++h) {
    const char* wbase = ap + WS_WTH_B + h * 32768;
    const float* bias = bh + h * 128;

    __builtin_amdgcn_s_setprio(1);
    // peeled ks = 0 : bias rides in as MFMA C operand
    {
      bf16x8 bfr[2];
      bfr[0] = __builtin_bit_cast(bf16x8, *reinterpret_cast<const uint4*>(Hs + va0));
      bfr[1] = __builtin_bit_cast(bf16x8, *reinterpret_cast<const uint4*>(Hs + va1));
#pragma unroll
      for (int nt = 0; nt < 8; ++nt) {
        const f32x4 bv = *reinterpret_cast<const f32x4*>(bias + nt * 16 + lh * 4);
        const bf16x8 a = __builtin_bit_cast(bf16x8,
            *reinterpret_cast<const uint4*>(wbase + nt * 1024));
        acc[nt][0] = __builtin_amdgcn_mfma_f32_16x16x32_bf16(a, bfr[0], bv, 0, 0, 0);
        acc[nt][1] = __builtin_amdgcn_mfma_f32_16x16x32_bf16(a, bfr[1], bv, 0, 0, 0);
      }
    }
#pragma unroll 1
    for (int ks = 1; ks < 4; ++ks) {
      bf16x8 bfr[2];
      bfr[0] = __builtin_bit_cast(bf16x8,
          *reinterpret_cast<const uint4*>(Hs + (va0 ^ (ks << 6))));
      bfr[1] = __builtin_bit_cast(bf16x8,
          *reinterpret_cast<const uint4*>(Hs + (va1 ^ (ks << 6))));
#pragma unroll
      for (int nt = 0; nt < 8; ++nt) {
        const bf16x8 a = __builtin_bit_cast(bf16x8,
            *reinterpret_cast<const uint4*>(wbase + (ks * 8 + nt) * 1024));
        acc[nt][0] = __builtin_amdgcn_mfma_f32_16x16x32_bf16(a, bfr[0], acc[nt][0], 0, 0, 0);
        acc[nt][1] = __builtin_amdgcn_mfma_f32_16x16x32_bf16(a, bfr[1], acc[nt][1], 0, 0, 0);
      }
    }
    __builtin_amdgcn_s_setprio(0);
#pragma unroll
    for (int nt = 0; nt < 8; ++nt) {
#pragma unroll
      for (int pt = 0; pt < 2; ++pt) {
        const uint2 wv = pack4(swish4(acc[nt][pt]));
        const int wa = (pt ? wa1 : wa0) ^ (nt << 5);
        *reinterpret_cast<uint2*>(Hs + wa) = wv;
      }
    }
  }

  // ================= final layer : [128 -> 2] via MFMA =================
  {
    const float bl0 = bL[0], bl1 = bL[1];
#pragma unroll
    for (int pt = 0; pt < 2; ++pt) {
      f32x4 accL = {0.f, 0.f, 0.f, 0.f};
#pragma unroll
      for (int ks = 0; ks < 4; ++ks) {
        const bf16x8 bfr = __builtin_bit_cast(bf16x8,
            *reinterpret_cast<const uint4*>(Hs + ((pt ? va1 : va0) ^ (ks << 6))));
        const bf16x8 a = __builtin_bit_cast(bf16x8,
            *reinterpret_cast<const uint4*>(ap + WS_WLT_B + ks * 1024));
        accL = __builtin_amdgcn_mfma_f32_16x16x32_bf16(a, bfr, accL, 0, 0, 0);
      }
      if (lh == 0) {
        const int p = pt * 16 + lm;
        float2 o;
        o.x = accL[0] + bl0;
        o.y = accL[1] + bl1;
        *reinterpret_cast<float2*>(out + (size_t)(row0 + p) * 2) = o;
      }
    }
  }
}

extern "C" void kernel_launch(void* const* d_in, const int* in_sizes, int n_in,
                              void* d_out, int out_size, void* d_ws, size_t ws_size,
                              hipStream_t stream) {
  const float* X     = (const float*)d_in[0];
  const float* numin = (const float*)d_in[1];
  const float* numax = (const float*)d_in[2];
  const float* W0    = (const float*)d_in[3];
  const float* b0    = (const float*)d_in[4];
  const float* Wh    = (const float*)d_in[5];
  const float* bh    = (const float*)d_in[6];
  const float* WL    = (const float*)d_in[7];
  const float* bL    = (const float*)d_in[8];
  unsigned short* ws = (unsigned short*)d_ws;
  float* out = (float*)d_out;

  hipLaunchKernelGGL(prep_kernel, dim3(344), dim3(256), 0, stream, W0, Wh, WL, ws);
  hipLaunchKernelGGL(mlp_kernel, dim3(4096), dim3(128), 0, stream,
                     X, numin, numax, b0, bh, bL, ws, out);
}

// Round 6
// 89.728 us; speedup vs baseline: 1.1558x; 1.1558x over previous
//
#include <hip/hip_runtime.h>

typedef __bf16 bf16x8 __attribute__((ext_vector_type(8)));
typedef float  f32x4  __attribute__((ext_vector_type(4)));

// ws layout (bytes). All A-operand fragments stored lane-linear:
// one frag = 1024 B; lane l's 16 B at frag_base + l*16 (fully coalesced load).
//   WT0 : 8 frags   (nt 0..7)            bytes [0      .. 8191  ]
//   WTH : 160 frags ((h*4+ks)*8 + nt)    bytes [8192   .. 172031]
//   WLT : 4 frags   (ks 0..3)            bytes [172032 .. 176127]
#define WS_WT0_B 0
#define WS_WTH_B 8192
#define WS_WLT_B 172032

__device__ __forceinline__ unsigned short f2b(float f) {
  return __builtin_bit_cast(unsigned short, (__bf16)f);
}

__global__ void prep_kernel(const float* __restrict__ W0,
                            const float* __restrict__ Wh,
                            const float* __restrict__ WL,
                            unsigned short* __restrict__ ws) {
  int i = blockIdx.x * 256 + threadIdx.x;   // ushort index == (byte/2)
  int l  = (i >> 3) & 63;                   // lane within frag
  int j  = i & 7;                           // element within lane's 8
  int lm = l & 15, lh = l >> 4;
  if (i < 4096) {                           // WT0, frag nt = i>>9 ; K=32 zero-padded
    int nt = i >> 9;
    int n = nt * 16 + lm, k = lh * 8 + j;
    ws[i] = f2b(k < 4 ? W0[k * 128 + n] : 0.f);
  } else if (i < 86016) {                   // WTH
    int t = i - 4096;
    int frag = t >> 9;                      // (h*4+ks)*8 + nt
    int nt = frag & 7, ks = (frag >> 3) & 3, h = frag >> 5;
    int n = nt * 16 + lm, k = ks * 32 + lh * 8 + j;
    ws[i] = f2b(Wh[(h * 128 + k) * 128 + n]);
  } else if (i < 88064) {                   // WLT, frag ks ; n>=2 zero-padded
    int t = i - 86016;
    int ks = t >> 9;
    int n = lm, k = ks * 32 + lh * 8 + j;
    ws[i] = f2b(n < 2 ? WL[k * 2 + n] : 0.f);
  }
}

__device__ __forceinline__ f32x4 swish4(f32x4 z) {
  f32x4 e;
  e[0] = __expf(-z[0]); e[1] = __expf(-z[1]);
  e[2] = __expf(-z[2]); e[3] = __expf(-z[3]);
  const f32x4 w = e + 1.f;                  // v_pk_add_f32 x2
  f32x4 s;
  s[0] = __builtin_amdgcn_rcpf(w[0]); s[1] = __builtin_amdgcn_rcpf(w[1]);
  s[2] = __builtin_amdgcn_rcpf(w[2]); s[3] = __builtin_amdgcn_rcpf(w[3]);
  return z * s;                             // v_pk_mul_f32 x2
}

// One wave per block; each wave owns 32 points through ALL layers. No barriers.
__launch_bounds__(64, 4)
__global__ void mlp_kernel(const float* __restrict__ X,
                           const float* __restrict__ nu_min_p,
                           const float* __restrict__ nu_max_p,
                           const float* __restrict__ b0,
                           const float* __restrict__ bh,
                           const float* __restrict__ bL,
                           const unsigned short* __restrict__ ws,
                           float* __restrict__ out) {
  __shared__ __align__(16) char Hs[32 * 256];   // [32 pt][128 ch] bf16, row-swizzled
  const int lane = threadIdx.x;                 // 0..63
  const int lm = lane & 15, lh = lane >> 4;
  const int row0 = blockIdx.x * 32;
  const char* wsb = reinterpret_cast<const char*>(ws);
  const int xorm = (lm & 7) << 4;               // p&7 == lm&7 for p = pt*16+lm

  // ---- stage scaled inputs (K padded to 32 -> 64B rows) ----
  if (lane < 32) {
    const float4 xv = reinterpret_cast<const float4*>(X)[row0 + lane];
    const float numin = nu_min_p[0], numax = nu_max_p[0];
    const float v0 = xv.x;                      // x already in [-1,1]
    const float v1 = xv.y;
    const float v2 = 2.f * xv.z - 1.f;
    const float v3 = 2.f * (xv.w - numin) / (numax - numin) - 1.f;
    uint4 c0;
    c0.x = (unsigned)f2b(v0) | ((unsigned)f2b(v1) << 16);
    c0.y = (unsigned)f2b(v2) | ((unsigned)f2b(v3) << 16);
    c0.z = 0u; c0.w = 0u;
    const uint4 z4 = make_uint4(0u, 0u, 0u, 0u);
    const int xr = (lane & 7) << 4;
    char* rp = Hs + lane * 256;
    *reinterpret_cast<uint4*>(rp + (0  ^ xr)) = c0;
    *reinterpret_cast<uint4*>(rp + (16 ^ xr)) = z4;
    *reinterpret_cast<uint4*>(rp + (32 ^ xr)) = z4;
    *reinterpret_cast<uint4*>(rp + (48 ^ xr)) = z4;
  }
  // single wave: DS ops are in-order per wave; no barrier needed anywhere.

  f32x4 acc[8][2];

  // ================= Layer 0 : K = 32 =================
  {
#pragma unroll
    for (int nt = 0; nt < 8; ++nt) {
      const f32x4 bv = *reinterpret_cast<const f32x4*>(b0 + nt * 16 + lh * 4);
      acc[nt][0] = bv; acc[nt][1] = bv;
    }
    bf16x8 bfr[2];
#pragma unroll
    for (int pt = 0; pt < 2; ++pt) {
      const int p = pt * 16 + lm;
      bfr[pt] = __builtin_bit_cast(bf16x8,
          *reinterpret_cast<const uint4*>(Hs + p * 256 + ((lh * 16) ^ xorm)));
    }
#pragma unroll
    for (int nt = 0; nt < 8; ++nt) {
      const bf16x8 a = __builtin_bit_cast(bf16x8,
          *reinterpret_cast<const uint4*>(wsb + WS_WT0_B + nt * 1024 + lane * 16));
      acc[nt][0] = __builtin_amdgcn_mfma_f32_16x16x32_bf16(a, bfr[0], acc[nt][0], 0, 0, 0);
      acc[nt][1] = __builtin_amdgcn_mfma_f32_16x16x32_bf16(a, bfr[1], acc[nt][1], 0, 0, 0);
    }
#pragma unroll
    for (int nt = 0; nt < 8; ++nt) {
#pragma unroll
      for (int pt = 0; pt < 2; ++pt) {
        const f32x4 r4 = swish4(acc[nt][pt]);
        unsigned short q0 = f2b(r4[0]), q1 = f2b(r4[1]), q2 = f2b(r4[2]), q3 = f2b(r4[3]);
        uint2 wv;
        wv.x = (unsigned)q0 | ((unsigned)q1 << 16);
        wv.y = (unsigned)q2 | ((unsigned)q3 << 16);
        const int p = pt * 16 + lm;
        *reinterpret_cast<uint2*>(Hs + p * 256 + (((nt * 16 + lh * 4) * 2) ^ xorm)) = wv;
      }
    }
  }

  // ================= 5 hidden layers : K = 128, in-place =================
  // ks loop fully unrolled so the compiler can hoist/pipeline all 32 A-frag
  // global loads of a layer ahead of the MFMAs (counted vmcnt instead of a
  // full-latency stall per ks step). h-loop stays rolled for code size.
#pragma unroll 1
  for (int h = 0; h < 5; ++h) {
    const char* wbase = wsb + WS_WTH_B + h * 32768;
    const float* bias = bh + h * 128;
#pragma unroll
    for (int nt = 0; nt < 8; ++nt) {
      const f32x4 bv = *reinterpret_cast<const f32x4*>(bias + nt * 16 + lh * 4);
      acc[nt][0] = bv; acc[nt][1] = bv;
    }
#pragma unroll
    for (int ks = 0; ks < 4; ++ks) {
      bf16x8 bfr[2];
#pragma unroll
      for (int pt = 0; pt < 2; ++pt) {
        const int p = pt * 16 + lm;
        bfr[pt] = __builtin_bit_cast(bf16x8,
            *reinterpret_cast<const uint4*>(Hs + p * 256 + ((ks * 64 + lh * 16) ^ xorm)));
      }
#pragma unroll
      for (int nt = 0; nt < 8; ++nt) {
        const bf16x8 a = __builtin_bit_cast(bf16x8,
            *reinterpret_cast<const uint4*>(wbase + (ks * 8 + nt) * 1024 + lane * 16));
        acc[nt][0] = __builtin_amdgcn_mfma_f32_16x16x32_bf16(a, bfr[0], acc[nt][0], 0, 0, 0);
        acc[nt][1] = __builtin_amdgcn_mfma_f32_16x16x32_bf16(a, bfr[1], acc[nt][1], 0, 0, 0);
      }
    }
#pragma unroll
    for (int nt = 0; nt < 8; ++nt) {
#pragma unroll
      for (int pt = 0; pt < 2; ++pt) {
        const f32x4 r4 = swish4(acc[nt][pt]);
        unsigned short q0 = f2b(r4[0]), q1 = f2b(r4[1]), q2 = f2b(r4[2]), q3 = f2b(r4[3]);
        uint2 wv;
        wv.x = (unsigned)q0 | ((unsigned)q1 << 16);
        wv.y = (unsigned)q2 | ((unsigned)q3 << 16);
        const int p = pt * 16 + lm;
        *reinterpret_cast<uint2*>(Hs + p * 256 + (((nt * 16 + lh * 4) * 2) ^ xorm)) = wv;
      }
    }
  }

  // ================= final layer : [128 -> 2] via MFMA =================
  {
    const float bl0 = bL[0], bl1 = bL[1];
#pragma unroll
    for (int pt2 = 0; pt2 < 2; ++pt2) {
      f32x4 accL = {0.f, 0.f, 0.f, 0.f};
      const int p = pt2 * 16 + lm;
#pragma unroll
      for (int ks = 0; ks < 4; ++ks) {
        const bf16x8 bfr = __builtin_bit_cast(bf16x8,
            *reinterpret_cast<const uint4*>(Hs + p * 256 + ((ks * 64 + lh * 16) ^ xorm)));
        const bf16x8 a = __builtin_bit_cast(bf16x8,
            *reinterpret_cast<const uint4*>(wsb + WS_WLT_B + ks * 1024 + lane * 16));
        accL = __builtin_amdgcn_mfma_f32_16x16x32_bf16(a, bfr, accL, 0, 0, 0);
      }
      if (lh == 0) {
        float2 o;
        o.x = accL[0] + bl0;
        o.y = accL[1] + bl1;
        *reinterpret_cast<float2*>(out + (size_t)(row0 + p) * 2) = o;
      }
    }
  }
}

extern "C" void kernel_launch(void* const* d_in, const int* in_sizes, int n_in,
                              void* d_out, int out_size, void* d_ws, size_t ws_size,
                              hipStream_t stream) {
  const float* X     = (const float*)d_in[0];
  const float* numin = (const float*)d_in[1];
  const float* numax = (const float*)d_in[2];
  const float* W0    = (const float*)d_in[3];
  const float* b0    = (const float*)d_in[4];
  const float* Wh    = (const float*)d_in[5];
  const float* bh    = (const float*)d_in[6];
  const float* WL    = (const float*)d_in[7];
  const float* bL    = (const float*)d_in[8];
  unsigned short* ws = (unsigned short*)d_ws;
  float* out = (float*)d_out;

  hipLaunchKernelGGL(prep_kernel, dim3(344), dim3(256), 0, stream, W0, Wh, WL, ws);
  hipLaunchKernelGGL(mlp_kernel, dim3(8192), dim3(64), 0, stream,
                     X, numin, numax, b0, bh, bL, ws, out);
}

// Round 7
// 78.259 us; speedup vs baseline: 1.3252x; 1.1466x over previous
//
#include <hip/hip_runtime.h>

typedef __bf16 bf16x8 __attribute__((ext_vector_type(8)));
typedef __bf16 bf16x2 __attribute__((ext_vector_type(2)));
typedef float  f32x4  __attribute__((ext_vector_type(4)));

// ws layout (bytes). All A-operand fragments lane-linear:
// one frag = 1024 B; lane l's 16 B at frag_base + l*16 (coalesced dwordx4).
//   WT0 : 8 frags   (nt 0..7, K=32 zero-padded)      [0      .. 8191  ]
//   WTH : 160 frags ((h*4+ks)*8 + nt)                [8192   .. 172031]
//   WLT : 8 frags   (ks 0..3 real, 4..7 zero pad)    [172032 .. 180223]
// WLT is padded to 8 frags so the continuous weight stream's last prefetch
// (layer h=4, phase 3: wb+32768+nt*1024, nt=0..7) stays inside our layout.
#define WS_WT0_B 0
#define WS_WTH_B 8192
#define WS_WLT_B 172032

__device__ __forceinline__ unsigned short f2b(float f) {
  return __builtin_bit_cast(unsigned short, (__bf16)f);
}

__global__ void prep_kernel(const float* __restrict__ W0,
                            const float* __restrict__ Wh,
                            const float* __restrict__ WL,
                            unsigned short* __restrict__ ws) {
  int i = blockIdx.x * 256 + threadIdx.x;   // ushort index == byte/2
  int l  = (i >> 3) & 63;                   // lane within frag
  int j  = i & 7;                           // element within lane's 8
  int lm = l & 15, lh = l >> 4;
  if (i < 4096) {                           // WT0
    int nt = i >> 9;
    int n = nt * 16 + lm, k = lh * 8 + j;
    ws[i] = f2b(k < 4 ? W0[k * 128 + n] : 0.f);
  } else if (i < 86016) {                   // WTH
    int t = i - 4096;
    int frag = t >> 9;                      // (h*4+ks)*8 + nt
    int nt = frag & 7, ks = (frag >> 3) & 3, h = frag >> 5;
    int n = nt * 16 + lm, k = ks * 32 + lh * 8 + j;
    ws[i] = f2b(Wh[(h * 128 + k) * 128 + n]);
  } else if (i < 90112) {                   // WLT (8 frags, 4 real + 4 zero)
    int t = i - 86016;
    int f = t >> 9;
    int k = (f & 3) * 32 + lh * 8 + j;
    ws[i] = f2b((f < 4 && lm < 2) ? WL[k * 2 + lm] : 0.f);
  }
}

__device__ __forceinline__ f32x4 swish4(f32x4 z) {
  f32x4 e;
  e[0] = __expf(-z[0]); e[1] = __expf(-z[1]);
  e[2] = __expf(-z[2]); e[3] = __expf(-z[3]);
  const f32x4 w = e + 1.f;
  f32x4 s;
  s[0] = __builtin_amdgcn_rcpf(w[0]); s[1] = __builtin_amdgcn_rcpf(w[1]);
  s[2] = __builtin_amdgcn_rcpf(w[2]); s[3] = __builtin_amdgcn_rcpf(w[3]);
  return z * s;
}

__device__ __forceinline__ uint2 pack4(f32x4 r) {   // v_cvt_pk_bf16_f32 path
  bf16x2 lo = {(__bf16)r[0], (__bf16)r[1]};
  bf16x2 hi = {(__bf16)r[2], (__bf16)r[3]};
  uint2 wv;
  wv.x = __builtin_bit_cast(unsigned int, lo);
  wv.y = __builtin_bit_cast(unsigned int, hi);
  return wv;
}

#define SB() __builtin_amdgcn_sched_barrier(0)
#define GLD(addr) __builtin_bit_cast(bf16x8, *reinterpret_cast<const uint4*>(addr))
#define LRD(addr) __builtin_bit_cast(bf16x8, *reinterpret_cast<const uint4*>(addr))
#define MFMA(a, b, c) __builtin_amdgcn_mfma_f32_16x16x32_bf16((a), (b), (c), 0, 0, 0)

// One wave per block; each wave owns 32 points through ALL layers. No barriers.
// 2-stage software pipeline on weight frags: aA/aB rotate, sched_barrier(0)
// pins phase boundaries so the compiler cannot merge load groups (R6 spill).
__launch_bounds__(64, 2)
__global__ void mlp_kernel(const float* __restrict__ X,
                           const float* __restrict__ nu_min_p,
                           const float* __restrict__ nu_max_p,
                           const float* __restrict__ b0,
                           const float* __restrict__ bh,
                           const float* __restrict__ bL,
                           const unsigned short* __restrict__ ws,
                           float* __restrict__ out) {
  __shared__ __align__(16) char smem[32 * 256 + 5 * 128 * 4];  // Hs + bh cache
  char* Hs = smem;
  float* bias_lds = reinterpret_cast<float*>(smem + 8192);
  const int lane = threadIdx.x;
  const int lm = lane & 15, lh = lane >> 4;
  const int row0 = blockIdx.x * 32;
  const char* ap = reinterpret_cast<const char*>(ws) + lane * 16;
  const int xorm = (lm & 7) << 4;
  // LDS addr bases; rd(pt,ks) = va[pt] ^ (ks<<6), wr(nt,pt) = wa[pt] ^ (nt<<5)
  const int va0 = lm * 256 + ((lh * 16) ^ xorm);
  const int va1 = va0 + 16 * 256;
  const int wa0 = lm * 256 + ((lh * 8) ^ xorm);
  const int wa1 = wa0 + 16 * 256;

  // ---- issue L0 weight frags + L0 bias (C-in) + bh staging loads up front ----
  bf16x8 aL0[8];
#pragma unroll
  for (int nt = 0; nt < 8; ++nt) aL0[nt] = GLD(ap + WS_WT0_B + nt * 1024);
  f32x4 bv0[8];
#pragma unroll
  for (int nt = 0; nt < 8; ++nt)
    bv0[nt] = *reinterpret_cast<const f32x4*>(b0 + nt * 16 + lh * 4);
  float bstg[10];
#pragma unroll
  for (int i = 0; i < 10; ++i) bstg[i] = bh[i * 64 + lane];

  // ---- stage scaled inputs (K padded to 32 -> 64B rows) ----
  if (lane < 32) {
    const float4 xv = reinterpret_cast<const float4*>(X)[row0 + lane];
    const float numin = nu_min_p[0], numax = nu_max_p[0];
    const float v0 = xv.x;
    const float v1 = xv.y;
    const float v2 = 2.f * xv.z - 1.f;
    const float v3 = 2.f * (xv.w - numin) / (numax - numin) - 1.f;
    uint4 c0;
    c0.x = (unsigned)f2b(v0) | ((unsigned)f2b(v1) << 16);
    c0.y = (unsigned)f2b(v2) | ((unsigned)f2b(v3) << 16);
    c0.z = 0u; c0.w = 0u;
    const uint4 z4 = make_uint4(0u, 0u, 0u, 0u);
    const int xr = (lane & 7) << 4;
    char* rp = Hs + lane * 256;
    *reinterpret_cast<uint4*>(rp + (0  ^ xr)) = c0;
    *reinterpret_cast<uint4*>(rp + (16 ^ xr)) = z4;
    *reinterpret_cast<uint4*>(rp + (32 ^ xr)) = z4;
    *reinterpret_cast<uint4*>(rp + (48 ^ xr)) = z4;
  }
  // bh -> LDS (consumed by hidden-layer epilogues)
#pragma unroll
  for (int i = 0; i < 10; ++i) bias_lds[i * 64 + lane] = bstg[i];

  f32x4 acc[8][2];
  bf16x8 bfrA[2], bfrB[2];
  bf16x8 aA[8], aB[8];

  // ================= Layer 0 : K = 32, bias as MFMA C-in =================
  bfrA[0] = LRD(Hs + va0);
  bfrA[1] = LRD(Hs + va1);
#pragma unroll
  for (int nt = 0; nt < 8; ++nt) {
    acc[nt][0] = MFMA(aL0[nt], bfrA[0], bv0[nt]);
    acc[nt][1] = MFMA(aL0[nt], bfrA[1], bv0[nt]);
  }
  // preload h=0 ks=0 weight frags (hidden under L0 epilogue)
#pragma unroll
  for (int nt = 0; nt < 8; ++nt) aA[nt] = GLD(ap + WS_WTH_B + nt * 1024);
  // L0 epilogue (bias already in acc)
#pragma unroll
  for (int nt = 0; nt < 8; ++nt) {
#pragma unroll
    for (int pt = 0; pt < 2; ++pt) {
      const uint2 wv = pack4(swish4(acc[nt][pt]));
      *reinterpret_cast<uint2*>(Hs + ((pt ? wa1 : wa0) ^ (nt << 5))) = wv;
    }
  }

  const f32x4 zero4 = {0.f, 0.f, 0.f, 0.f};

  // ============ 5 hidden layers : explicit 2-stage pipelined phases ============
#pragma unroll 1
  for (int h = 0; h < 5; ++h) {
    const char* wb = ap + WS_WTH_B + h * 32768;
    const float* bl = bias_lds + h * 128;

    // phase 0: compute with aA/bfrA(ks0); prefetch aB,bfrB <- ks1
    bfrA[0] = LRD(Hs + va0);
    bfrA[1] = LRD(Hs + va1);
#pragma unroll
    for (int nt = 0; nt < 8; ++nt) aB[nt] = GLD(wb + 8192 + nt * 1024);
    bfrB[0] = LRD(Hs + (va0 ^ 64));
    bfrB[1] = LRD(Hs + (va1 ^ 64));
#pragma unroll
    for (int nt = 0; nt < 8; ++nt) {
      acc[nt][0] = MFMA(aA[nt], bfrA[0], zero4);
      acc[nt][1] = MFMA(aA[nt], bfrA[1], zero4);
    }
    SB();
    // phase 1: compute with aB/bfrB(ks1); prefetch aA,bfrA <- ks2
#pragma unroll
    for (int nt = 0; nt < 8; ++nt) aA[nt] = GLD(wb + 16384 + nt * 1024);
    bfrA[0] = LRD(Hs + (va0 ^ 128));
    bfrA[1] = LRD(Hs + (va1 ^ 128));
#pragma unroll
    for (int nt = 0; nt < 8; ++nt) {
      acc[nt][0] = MFMA(aB[nt], bfrB[0], acc[nt][0]);
      acc[nt][1] = MFMA(aB[nt], bfrB[1], acc[nt][1]);
    }
    SB();
    // phase 2: compute with aA/bfrA(ks2); prefetch aB,bfrB <- ks3
#pragma unroll
    for (int nt = 0; nt < 8; ++nt) aB[nt] = GLD(wb + 24576 + nt * 1024);
    bfrB[0] = LRD(Hs + (va0 ^ 192));
    bfrB[1] = LRD(Hs + (va1 ^ 192));
#pragma unroll
    for (int nt = 0; nt < 8; ++nt) {
      acc[nt][0] = MFMA(aA[nt], bfrA[0], acc[nt][0]);
      acc[nt][1] = MFMA(aA[nt], bfrA[1], acc[nt][1]);
    }
    SB();
    // phase 3: compute with aB/bfrB(ks3); prefetch aA <- next ks0 (continuous
    // stream: at h=4 this lands on WLT -> final-layer weights in registers)
#pragma unroll
    for (int nt = 0; nt < 8; ++nt) aA[nt] = GLD(wb + 32768 + nt * 1024);
#pragma unroll
    for (int nt = 0; nt < 8; ++nt) {
      acc[nt][0] = MFMA(aB[nt], bfrB[0], acc[nt][0]);
      acc[nt][1] = MFMA(aB[nt], bfrB[1], acc[nt][1]);
    }
    SB();
    // epilogue: bias (LDS) + swish -> bf16 pack -> Hs (in place)
#pragma unroll
    for (int nt = 0; nt < 8; ++nt) {
      const f32x4 bv = *reinterpret_cast<const f32x4*>(bl + nt * 16 + lh * 4);
#pragma unroll
      for (int pt = 0; pt < 2; ++pt) {
        const uint2 wv = pack4(swish4(acc[nt][pt] + bv));
        *reinterpret_cast<uint2*>(Hs + ((pt ? wa1 : wa0) ^ (nt << 5))) = wv;
      }
    }
  }

  // ================= final layer : [128 -> 2], weights already in aA =================
  {
    const float bl0 = bL[0], bl1 = bL[1];
#pragma unroll
    for (int pt = 0; pt < 2; ++pt) {
      f32x4 accL = {0.f, 0.f, 0.f, 0.f};
#pragma unroll
      for (int ks = 0; ks < 4; ++ks) {
        const bf16x8 bfr = LRD(Hs + ((pt ? va1 : va0) ^ (ks << 6)));
        accL = MFMA(aA[ks], bfr, accL);
      }
      if (lh == 0) {
        const int p = pt * 16 + lm;
        float2 o;
        o.x = accL[0] + bl0;
        o.y = accL[1] + bl1;
        *reinterpret_cast<float2*>(out + (size_t)(row0 + p) * 2) = o;
      }
    }
  }
}

extern "C" void kernel_launch(void* const* d_in, const int* in_sizes, int n_in,
                              void* d_out, int out_size, void* d_ws, size_t ws_size,
                              hipStream_t stream) {
  const float* X     = (const float*)d_in[0];
  const float* numin = (const float*)d_in[1];
  const float* numax = (const float*)d_in[2];
  const float* W0    = (const float*)d_in[3];
  const float* b0    = (const float*)d_in[4];
  const float* Wh    = (const float*)d_in[5];
  const float* bh    = (const float*)d_in[6];
  const float* WL    = (const float*)d_in[7];
  const float* bL    = (const float*)d_in[8];
  unsigned short* ws = (unsigned short*)d_ws;
  float* out = (float*)d_out;

  hipLaunchKernelGGL(prep_kernel, dim3(352), dim3(256), 0, stream, W0, Wh, WL, ws);
  hipLaunchKernelGGL(mlp_kernel, dim3(8192), dim3(64), 0, stream,
                     X, numin, numax, b0, bh, bL, ws, out);
}